// Round 10
// baseline (481.780 us; speedup 1.0000x reference)
//
#include <hip/hip_runtime.h>

#define BATCH 4096
#define DIM   512
#define NROW  8192
#define TILE  256
#define NCH   32                      // 256-row/col chunks
#define NBLK  (NCH * (NCH + 1) / 2)   // 528 triangle cells (incl. diagonal)
#define NSLOT 32

typedef __attribute__((ext_vector_type(8))) short bf16x8;
typedef __attribute__((ext_vector_type(4))) float f32x4;

__device__ inline unsigned short f2bf(float f) {
    unsigned int u = __float_as_uint(f);
    u += 0x7fffu + ((u >> 16) & 1u);
    return (unsigned short)(u >> 16);
}

__device__ __forceinline__ void gload16(const unsigned short* g, unsigned short* l) {
    __builtin_amdgcn_global_load_lds(
        (const __attribute__((address_space(1))) void*)g,
        (__attribute__((address_space(3))) void*)l, 16, 0, 0);
}

// ---------------- Kernel 1: normalize rows + positives ----------------
__global__ __launch_bounds__(256) void normalize_pos_kernel(
    const float* __restrict__ ei, const float* __restrict__ ej,
    unsigned short* __restrict__ reps, float* __restrict__ pos) {
    const int t = threadIdx.x & 63;
    const int i = blockIdx.x * 4 + (threadIdx.x >> 6);

    const float4* ri = (const float4*)(ei + (size_t)i * DIM);
    const float4* rj = (const float4*)(ej + (size_t)i * DIM);
    float4 a0 = ri[t], a1 = ri[t + 64];
    float4 b0 = rj[t], b1 = rj[t + 64];

    float si  = a0.x*a0.x + a0.y*a0.y + a0.z*a0.z + a0.w*a0.w
              + a1.x*a1.x + a1.y*a1.y + a1.z*a1.z + a1.w*a1.w;
    float sj  = b0.x*b0.x + b0.y*b0.y + b0.z*b0.z + b0.w*b0.w
              + b1.x*b1.x + b1.y*b1.y + b1.z*b1.z + b1.w*b1.w;
    float dij = a0.x*b0.x + a0.y*b0.y + a0.z*b0.z + a0.w*b0.w
              + a1.x*b1.x + a1.y*b1.y + a1.z*b1.z + a1.w*b1.w;

    #pragma unroll
    for (int m = 1; m < 64; m <<= 1) {
        si  += __shfl_xor(si,  m);
        sj  += __shfl_xor(sj,  m);
        dij += __shfl_xor(dij, m);
    }
    float invi = 1.0f / fmaxf(sqrtf(si), 1e-12f);
    float invj = 1.0f / fmaxf(sqrtf(sj), 1e-12f);

    ushort4 o0, o1, p0, p1;
    o0.x = f2bf(a0.x*invi); o0.y = f2bf(a0.y*invi); o0.z = f2bf(a0.z*invi); o0.w = f2bf(a0.w*invi);
    o1.x = f2bf(a1.x*invi); o1.y = f2bf(a1.y*invi); o1.z = f2bf(a1.z*invi); o1.w = f2bf(a1.w*invi);
    p0.x = f2bf(b0.x*invj); p0.y = f2bf(b0.y*invj); p0.z = f2bf(b0.z*invj); p0.w = f2bf(b0.w*invj);
    p1.x = f2bf(b1.x*invj); p1.y = f2bf(b1.y*invj); p1.z = f2bf(b1.z*invj); p1.w = f2bf(b1.w*invj);

    ushort4* wi = (ushort4*)(reps + (size_t)i * DIM);
    ushort4* wj = (ushort4*)(reps + (size_t)(BATCH + i) * DIM);
    wi[t] = o0; wi[t + 64] = o1;
    wj[t] = p0; wj[t + 64] = p1;
    if (t == 0) pos[i] = dij * invi * invj;
}

// ---------------- Kernel 2: triangle 256x256 cells, 2 blocks/CU ----------
// r6's proven inner loop (12 ds_read -> lgkm(0) -> 32 MFMA, 1 barrier/K-step,
// setprio, zero-conflict swizzle) with ring-2 LDS (64 KB) so TWO blocks
// co-reside per CU: sibling block's MFMA covers this block's stalls (m114).
// T3-minimum recipe: STAGE(other slot, t+1) at iter start; vmcnt(0)+barrier
// at iter end (stage has ~2.4K cy of cover).
__global__ __launch_bounds__(512, 4) void simsum_kernel(
    const unsigned short* __restrict__ reps, float* __restrict__ partials) {
    __shared__ unsigned short lds[2][16384];   // slot: A 256x32 | B 256x32 (32 KB)

    int bid = (blockIdx.x & 7) * (NBLK / 8) + (blockIdx.x >> 3);  // 528 = 8*66
    int rc = 0, b = bid;
    while (b >= NCH - rc) { b -= NCH - rc; ++rc; }
    const int cc = rc + b;                    // rc <= cc
    const bool isDiag = (rc == cc);

    const int tid  = threadIdx.x;
    const int lane = tid & 63;
    const int wave = tid >> 6;
    const int wr = wave >> 2, wc = wave & 3;
    const int s = lane & 15, q = lane >> 4;
    const int rowBase = rc * TILE, colBase = cc * TILE;

    // staging: wave w owns rows [32w, 32w+32) of A and B; pre-swizzled source
    const int lr = lane >> 2;                                  // row-in-16
    const int g8 = (((lane & 3) ^ ((lane >> 2) & 3) ^ (lane >> 4)) & 3) * 8;
    const unsigned short* gAw = reps + (size_t)(rowBase + wave * 32 + lr) * DIM + g8;
    const unsigned short* gBw = reps + (size_t)(colBase + wave * 32 + lr) * DIM + g8;

    // ds_read swizzled byte offsets (r6-verified conflict-free)
    const int sig  = ((s & 3) ^ (s >> 2)) & 3;
    const int koS  = ((q ^ sig) & 3) << 4;
    const int aoff = (wr * 128 + s) * 64 + koS;                // + m*1024
    const int boff = 16384 + (wc * 64 + s) * 64 + koS;         // + n*1024 (B at byte 16384)

    f32x4 acc[8][4];
    #pragma unroll
    for (int m = 0; m < 8; ++m)
        #pragma unroll
        for (int n = 0; n < 4; ++n) acc[m][n] = (f32x4){0.f,0.f,0.f,0.f};

#define STAGE(t) do { \
        const int _kb = (t) * 32; \
        unsigned short* _sb = &lds[(t) & 1][0]; \
        gload16(gAw + _kb,            _sb + wave * 1024); \
        gload16(gAw + 16 * DIM + _kb, _sb + wave * 1024 + 512); \
        gload16(gBw + _kb,            _sb + 8192 + wave * 1024); \
        gload16(gBw + 16 * DIM + _kb, _sb + 8192 + wave * 1024 + 512); \
    } while (0)

    // prologue: stage K-step 0 into slot 0
    STAGE(0);
    asm volatile("s_waitcnt vmcnt(0)" ::: "memory");
    __builtin_amdgcn_s_barrier();
    __builtin_amdgcn_sched_barrier(0);

    #pragma unroll
    for (int t = 0; t < 16; ++t) {
        // stage NEXT K-step into the other slot (no readers: they finished
        // before the barrier that ended iter t-1)
        if (t < 15) STAGE(t + 1);

        const char* base = (const char*)&lds[t & 1][0];
        bf16x8 af[4], ag[4], bf[4];
        #pragma unroll
        for (int m = 0; m < 4; ++m) af[m] = *(const bf16x8*)(base + aoff + m * 1024);
        #pragma unroll
        for (int n = 0; n < 4; ++n) bf[n] = *(const bf16x8*)(base + boff + n * 1024);
        #pragma unroll
        for (int m = 0; m < 4; ++m) ag[m] = *(const bf16x8*)(base + aoff + (4 + m) * 1024);

        asm volatile("s_waitcnt lgkmcnt(0)" ::: "memory");
        __builtin_amdgcn_sched_barrier(0);
        __builtin_amdgcn_s_setprio(1);
        #pragma unroll
        for (int m = 0; m < 4; ++m)
            #pragma unroll
            for (int n = 0; n < 4; ++n)
                acc[m][n] = __builtin_amdgcn_mfma_f32_16x16x32_bf16(
                    af[m], bf[n], acc[m][n], 0, 0, 0);
        #pragma unroll
        for (int m = 0; m < 4; ++m)
            #pragma unroll
            for (int n = 0; n < 4; ++n)
                acc[4 + m][n] = __builtin_amdgcn_mfma_f32_16x16x32_bf16(
                    ag[m], bf[n], acc[4 + m][n], 0, 0, 0);
        __builtin_amdgcn_s_setprio(0);

        // drain this iter's stage (issued ~2.4K cy ago), then publish slot
        if (t < 15) { asm volatile("s_waitcnt vmcnt(0)" ::: "memory"); }
        __builtin_amdgcn_s_barrier();
        __builtin_amdgcn_sched_barrier(0);
    }
#undef STAGE

    // ---- epilogue: exp(sim/T); diag masked; row + col sums ----
    const float SCALE = 2.8853900817779268f;   // 2/ln2
    float* red = (float*)lds;                  // [4][256] rowsum | [2][256] colsum
    __syncthreads();
    float colacc[4] = {0.f,0.f,0.f,0.f};
    #pragma unroll
    for (int m = 0; m < 8; ++m) {
        const int lrow0 = wr * 128 + m * 16 + (q << 2);
        const int grow0 = rowBase + lrow0;
        float rs[4] = {0.f,0.f,0.f,0.f};
        #pragma unroll
        for (int n = 0; n < 4; ++n) {
            const int gcol = colBase + wc * 64 + n * 16 + s;
            #pragma unroll
            for (int j = 0; j < 4; ++j) {
                float e = exp2f(acc[m][n][j] * SCALE);
                if (isDiag && (grow0 + j == gcol)) e = 0.f;
                rs[j] += e;
                colacc[n] += e;
            }
        }
        #pragma unroll
        for (int j = 0; j < 4; ++j) {
            float v = rs[j];
            v += __shfl_xor(v, 1); v += __shfl_xor(v, 2);
            v += __shfl_xor(v, 4); v += __shfl_xor(v, 8);
            if (s == 0) red[wc * 256 + lrow0 + j] = v;
        }
    }
    #pragma unroll
    for (int n = 0; n < 4; ++n) {
        float v = colacc[n];
        v += __shfl_xor(v, 16); v += __shfl_xor(v, 32);
        if (q == 0) red[1024 + wr * 256 + wc * 64 + n * 16 + s] = v;
    }
    __syncthreads();
    if (tid < 256) {
        partials[(size_t)cc * NROW + rowBase + tid] =
            red[tid] + red[256 + tid] + red[512 + tid] + red[768 + tid];
        if (!isDiag)
            partials[(size_t)rc * NROW + colBase + tid] =
                red[1024 + tid] + red[1280 + tid];
    }
}

// ---------------- Kernel 3a: per-row loss partial sums ----------------
__global__ __launch_bounds__(256) void rowloss_kernel(
    const float* __restrict__ partials, const float* __restrict__ pos,
    double* __restrict__ blocksum) {
    const int t = threadIdx.x;
    const int r = blockIdx.x * 256 + t;
    float denom = 0.f;
    #pragma unroll 8
    for (int c = 0; c < NSLOT; ++c)
        denom += partials[(size_t)c * NROW + r];
    double v = (double)(logf(denom) - 2.0f * pos[r & (BATCH - 1)]);
    __shared__ double redl[256];
    redl[t] = v;
    __syncthreads();
    for (int off = 128; off > 0; off >>= 1) {
        if (t < off) redl[t] += redl[t + off];
        __syncthreads();
    }
    if (t == 0) blocksum[blockIdx.x] = redl[0];
}

__global__ void final2_kernel(const double* __restrict__ blocksum,
                              float* __restrict__ out) {
    if (threadIdx.x == 0) {
        double ssum = 0.0;
        #pragma unroll
        for (int i = 0; i < NROW / 256; ++i) ssum += blocksum[i];
        out[0] = (float)(ssum / (double)NROW);
    }
}

extern "C" void kernel_launch(void* const* d_in, const int* in_sizes, int n_in,
                              void* d_out, int out_size, void* d_ws, size_t ws_size,
                              hipStream_t stream) {
    const float* ei = (const float*)d_in[0];
    const float* ej = (const float*)d_in[1];
    float* out = (float*)d_out;

    unsigned short* reps = (unsigned short*)d_ws;                       // 8 MB
    float* pos      = (float*)((char*)d_ws + (size_t)NROW * DIM * 2);   // 16 KB
    float* partials = pos + BATCH;                                      // 32*8192*4
    double* blocksum = (double*)(partials + (size_t)NSLOT * NROW);

    normalize_pos_kernel<<<BATCH / 4, 256, 0, stream>>>(ei, ej, reps, pos);
    simsum_kernel<<<NBLK, 512, 0, stream>>>(reps, partials);
    rowloss_kernel<<<NROW / 256, 256, 0, stream>>>(partials, pos, blocksum);
    final2_kernel<<<1, 64, 0, stream>>>(blocksum, out);
}

// Round 11
// 77.310 us; speedup vs baseline: 6.2318x; 6.2318x over previous
//
#include <hip/hip_runtime.h>

#define BATCH 4096
#define DIM   512
#define NROW  8192
#define TILE  256
#define NCH   32                      // 256-row/col chunks
#define NBLK  (NCH * (NCH + 1) / 2)   // 528 triangle cells (incl. diagonal)
#define NSLOT 32
#define NT8   8                       // K-steps of 64 (fp8 bytes)

typedef __attribute__((ext_vector_type(4))) float f32x4;

// ---- f32 -> fp8 e4m3fn, round-to-nearest-even (|x| <= 1 here, no sat path) ----
__device__ inline unsigned f2fp8(float f) {
    unsigned u = __float_as_uint(f);
    unsigned s = (u >> 31) << 7;
    unsigned mag = u & 0x7fffffffu;
    // RNE on contiguous (exp<<3 | mant3): carry propagates into exponent
    unsigned q = (mag + 0x7FFFFu + ((mag >> 20) & 1u)) >> 20;
    int e8 = (int)(q >> 3) - 120;
    if (e8 >= 1) return s | ((unsigned)e8 << 3) | (q & 7u);   // normal
    float t = __uint_as_float(mag) * 512.0f;                  // subnormal: 2^-9 quantum
    return s | (unsigned)rintf(t);                            // carry to 8 == 2^-6, correct
}

__device__ __forceinline__ void gload16(const unsigned char* g, unsigned char* l) {
    __builtin_amdgcn_global_load_lds(
        (const __attribute__((address_space(1))) void*)g,
        (__attribute__((address_space(3))) void*)l, 16, 0, 0);
}

__device__ __forceinline__ long mklong(unsigned lo, unsigned hi) {
    return (long)(((unsigned long long)hi << 32) | lo);
}

// ---------------- Kernel 1: normalize rows + positives -> fp8 reps ----------
// K-permuted fp8 layout per 64-col block: pos p = q*16 + h*8 + b holds
// k = b + h*32 + q*8, so a b128 LDS read yields both K32-half fragments.
__global__ __launch_bounds__(256) void normalize_pos_kernel(
    const float* __restrict__ ei, const float* __restrict__ ej,
    unsigned char* __restrict__ reps, float* __restrict__ pos) {
    const int t = threadIdx.x & 63;
    const int i = blockIdx.x * 4 + (threadIdx.x >> 6);

    const float4* ri = (const float4*)(ei + (size_t)i * DIM);
    const float4* rj = (const float4*)(ej + (size_t)i * DIM);
    float4 a0 = ri[t], a1 = ri[t + 64];
    float4 b0 = rj[t], b1 = rj[t + 64];

    float si  = a0.x*a0.x + a0.y*a0.y + a0.z*a0.z + a0.w*a0.w
              + a1.x*a1.x + a1.y*a1.y + a1.z*a1.z + a1.w*a1.w;
    float sj  = b0.x*b0.x + b0.y*b0.y + b0.z*b0.z + b0.w*b0.w
              + b1.x*b1.x + b1.y*b1.y + b1.z*b1.z + b1.w*b1.w;
    float dij = a0.x*b0.x + a0.y*b0.y + a0.z*b0.z + a0.w*b0.w
              + a1.x*b1.x + a1.y*b1.y + a1.z*b1.z + a1.w*b1.w;

    #pragma unroll
    for (int m = 1; m < 64; m <<= 1) {
        si  += __shfl_xor(si,  m);
        sj  += __shfl_xor(sj,  m);
        dij += __shfl_xor(dij, m);
    }
    float invi = 1.0f / fmaxf(sqrtf(si), 1e-12f);
    float invj = 1.0f / fmaxf(sqrtf(sj), 1e-12f);

    // byte offsets within the 512-byte row for k=4t (and +256 for k=256+4t)
    const int off0 = (t >> 4) * 64 + ((t >> 1) & 3) * 16 + ((t >> 3) & 1) * 8 + 4 * (t & 1);

    unsigned wa0 = f2fp8(a0.x*invi) | (f2fp8(a0.y*invi) << 8)
                 | (f2fp8(a0.z*invi) << 16) | (f2fp8(a0.w*invi) << 24);
    unsigned wa1 = f2fp8(a1.x*invi) | (f2fp8(a1.y*invi) << 8)
                 | (f2fp8(a1.z*invi) << 16) | (f2fp8(a1.w*invi) << 24);
    unsigned wb0 = f2fp8(b0.x*invj) | (f2fp8(b0.y*invj) << 8)
                 | (f2fp8(b0.z*invj) << 16) | (f2fp8(b0.w*invj) << 24);
    unsigned wb1 = f2fp8(b1.x*invj) | (f2fp8(b1.y*invj) << 8)
                 | (f2fp8(b1.z*invj) << 16) | (f2fp8(b1.w*invj) << 24);

    unsigned char* wi = reps + (size_t)i * DIM;
    unsigned char* wj = reps + (size_t)(BATCH + i) * DIM;
    *(unsigned*)(wi + off0)       = wa0;
    *(unsigned*)(wi + off0 + 256) = wa1;
    *(unsigned*)(wj + off0)       = wb0;
    *(unsigned*)(wj + off0 + 256) = wb1;
    if (t == 0) pos[i] = dij * invi * invj;
}

// ---------------- Kernel 2: triangle 256x256 cells, fp8 MFMA ----------------
// r6's proven schedule: ring-4 LDS slots (32 KB each), depth-3 prefetch,
// counted vmcnt(8), 1 barrier per K-step, 12 ds_read_b128 -> lgkm(0) ->
// setprio + 64 MFMA (fp8, two K32 halves per read). 8 K64-steps.
__global__ __launch_bounds__(512, 2) void simsum_kernel(
    const unsigned char* __restrict__ reps, float* __restrict__ partials) {
    __shared__ unsigned char lds[4][32768];   // slot: A [256][64B] | B [256][64B]

    int bid = (blockIdx.x & 7) * (NBLK / 8) + (blockIdx.x >> 3);  // 528 = 8*66
    int rc = 0, b = bid;
    while (b >= NCH - rc) { b -= NCH - rc; ++rc; }
    const int cc = rc + b;                    // rc <= cc
    const bool isDiag = (rc == cc);

    const int tid  = threadIdx.x;
    const int lane = tid & 63;
    const int wave = tid >> 6;
    const int wr = wave >> 2, wc = wave & 3;
    const int s = lane & 15, q = lane >> 4;
    const int rowBase = rc * TILE, colBase = cc * TILE;

    // staging: wave owns rows [32w,32w+32); pre-swizzled 16B-slot source
    const int lr = lane >> 2;                                  // row-in-16
    const int gb = (((lane & 3) ^ ((lane >> 2) & 3) ^ (lane >> 4)) & 3) * 16;  // bytes
    const unsigned char* gAw = reps + (size_t)(rowBase + wave * 32 + lr) * DIM + gb;
    const unsigned char* gBw = reps + (size_t)(colBase + wave * 32 + lr) * DIM + gb;

    // ds_read swizzled byte offsets (identical constants to r6: 64B rows)
    const int sig  = ((s & 3) ^ (s >> 2)) & 3;
    const int koS  = ((q ^ sig) & 3) << 4;
    const int aoff = (wr * 128 + s) * 64 + koS;                // + m*1024
    const int boff = 16384 + (wc * 64 + s) * 64 + koS;         // + n*1024

    f32x4 acc[8][4];
    #pragma unroll
    for (int m = 0; m < 8; ++m)
        #pragma unroll
        for (int n = 0; n < 4; ++n) acc[m][n] = (f32x4){0.f,0.f,0.f,0.f};

#define STAGE(t) do { \
        const int _kb = (t) * 64; \
        unsigned char* _sb = &lds[(t) & 3][0]; \
        gload16(gAw + _kb,             _sb + wave * 2048); \
        gload16(gAw + 16 * DIM + _kb,  _sb + wave * 2048 + 1024); \
        gload16(gBw + _kb,             _sb + 16384 + wave * 2048); \
        gload16(gBw + 16 * DIM + _kb,  _sb + 16384 + wave * 2048 + 1024); \
    } while (0)

    // prologue: stage K-steps 0,1,2 (12 gloads/wave)
    STAGE(0); STAGE(1); STAGE(2);

    #pragma unroll
    for (int t = 0; t < NT8; ++t) {
        // slot t complete after this wait (4 gloads/wave/step; depth-3 ring)
        if (t <= 5)       { asm volatile("s_waitcnt vmcnt(8)" ::: "memory"); }
        else if (t == 6)  { asm volatile("s_waitcnt vmcnt(4)" ::: "memory"); }
        else              { asm volatile("s_waitcnt vmcnt(0)" ::: "memory"); }
        __builtin_amdgcn_s_barrier();
        __builtin_amdgcn_sched_barrier(0);

        if (t + 3 < NT8) STAGE(t + 3);

        const char* base = (const char*)&lds[t & 3][0];
        int4 af[8], bf[4];
        #pragma unroll
        for (int m = 0; m < 8; ++m) af[m] = *(const int4*)(base + aoff + m * 1024);
        #pragma unroll
        for (int n = 0; n < 4; ++n) bf[n] = *(const int4*)(base + boff + n * 1024);

        asm volatile("s_waitcnt lgkmcnt(0)" ::: "memory");
        __builtin_amdgcn_sched_barrier(0);
        __builtin_amdgcn_s_setprio(1);
        #pragma unroll
        for (int m = 0; m < 8; ++m) {
            const long aL = mklong((unsigned)af[m].x, (unsigned)af[m].y);
            const long aH = mklong((unsigned)af[m].z, (unsigned)af[m].w);
            #pragma unroll
            for (int n = 0; n < 4; ++n) {
                const long bL = mklong((unsigned)bf[n].x, (unsigned)bf[n].y);
                const long bH = mklong((unsigned)bf[n].z, (unsigned)bf[n].w);
                acc[m][n] = __builtin_amdgcn_mfma_f32_16x16x32_fp8_fp8(
                    aL, bL, acc[m][n], 0, 0, 0);
                acc[m][n] = __builtin_amdgcn_mfma_f32_16x16x32_fp8_fp8(
                    aH, bH, acc[m][n], 0, 0, 0);
            }
        }
        __builtin_amdgcn_s_setprio(0);
    }
#undef STAGE

    // ---- epilogue: exp(sim/T); diag masked; row + col sums ----
    const float SCALE = 2.8853900817779268f;   // 2/ln2
    float* red = (float*)lds;                  // [4][256] rowsum | [2][256] colsum
    __syncthreads();
    float colacc[4] = {0.f,0.f,0.f,0.f};
    #pragma unroll
    for (int m = 0; m < 8; ++m) {
        const int lrow0 = wr * 128 + m * 16 + (q << 2);
        const int grow0 = rowBase + lrow0;
        float rs[4] = {0.f,0.f,0.f,0.f};
        #pragma unroll
        for (int n = 0; n < 4; ++n) {
            const int gcol = colBase + wc * 64 + n * 16 + s;
            #pragma unroll
            for (int j = 0; j < 4; ++j) {
                float e = exp2f(acc[m][n][j] * SCALE);
                if (isDiag && (grow0 + j == gcol)) e = 0.f;
                rs[j] += e;
                colacc[n] += e;
            }
        }
        #pragma unroll
        for (int j = 0; j < 4; ++j) {
            float v = rs[j];
            v += __shfl_xor(v, 1); v += __shfl_xor(v, 2);
            v += __shfl_xor(v, 4); v += __shfl_xor(v, 8);
            if (s == 0) red[wc * 256 + lrow0 + j] = v;
        }
    }
    #pragma unroll
    for (int n = 0; n < 4; ++n) {
        float v = colacc[n];
        v += __shfl_xor(v, 16); v += __shfl_xor(v, 32);
        if (q == 0) red[1024 + wr * 256 + wc * 64 + n * 16 + s] = v;
    }
    __syncthreads();
    if (tid < 256) {
        partials[(size_t)cc * NROW + rowBase + tid] =
            red[tid] + red[256 + tid] + red[512 + tid] + red[768 + tid];
        if (!isDiag)
            partials[(size_t)rc * NROW + colBase + tid] =
                red[1024 + tid] + red[1280 + tid];
    }
}

// ---------------- Kernel 3a: per-row loss partial sums ----------------
__global__ __launch_bounds__(256) void rowloss_kernel(
    const float* __restrict__ partials, const float* __restrict__ pos,
    double* __restrict__ blocksum) {
    const int t = threadIdx.x;
    const int r = blockIdx.x * 256 + t;
    float denom = 0.f;
    #pragma unroll 8
    for (int c = 0; c < NSLOT; ++c)
        denom += partials[(size_t)c * NROW + r];
    double v = (double)(logf(denom) - 2.0f * pos[r & (BATCH - 1)]);
    __shared__ double redl[256];
    redl[t] = v;
    __syncthreads();
    for (int off = 128; off > 0; off >>= 1) {
        if (t < off) redl[t] += redl[t + off];
        __syncthreads();
    }
    if (t == 0) blocksum[blockIdx.x] = redl[0];
}

__global__ void final2_kernel(const double* __restrict__ blocksum,
                              float* __restrict__ out) {
    if (threadIdx.x == 0) {
        double ssum = 0.0;
        #pragma unroll
        for (int i = 0; i < NROW / 256; ++i) ssum += blocksum[i];
        out[0] = (float)(ssum / (double)NROW);
    }
}

extern "C" void kernel_launch(void* const* d_in, const int* in_sizes, int n_in,
                              void* d_out, int out_size, void* d_ws, size_t ws_size,
                              hipStream_t stream) {
    const float* ei = (const float*)d_in[0];
    const float* ej = (const float*)d_in[1];
    float* out = (float*)d_out;

    unsigned char* reps = (unsigned char*)d_ws;                         // 4 MB fp8
    float* pos      = (float*)((char*)d_ws + (size_t)NROW * DIM);       // 16 KB
    float* partials = pos + BATCH;                                      // 32*8192*4
    double* blocksum = (double*)(partials + (size_t)NSLOT * NROW);

    normalize_pos_kernel<<<BATCH / 4, 256, 0, stream>>>(ei, ej, reps, pos);
    simsum_kernel<<<NBLK, 512, 0, stream>>>(reps, partials);
    rowloss_kernel<<<NROW / 256, 256, 0, stream>>>(partials, pos, blocksum);
    final2_kernel<<<1, 64, 0, stream>>>(blocksum, out);
}

// Round 12
// 74.472 us; speedup vs baseline: 6.4693x; 1.0381x over previous
//
#include <hip/hip_runtime.h>

#define BATCH 4096
#define DIM   512
#define NROW  8192
#define TILE  256
#define NCH   32                      // 256-row/col chunks
#define NBLK  (NCH * (NCH + 1) / 2)   // 528 triangle cells (incl. diagonal)
#define NSLOT 32
#define NT8   8                       // K-steps of 64 (fp8 bytes)

typedef __attribute__((ext_vector_type(4))) float f32x4;
typedef __attribute__((ext_vector_type(2))) long long2v;

// ---- f32 -> fp8 e4m3fn, round-to-nearest-even (|x| <= 1 here, no sat path) ----
__device__ inline unsigned f2fp8(float f) {
    unsigned u = __float_as_uint(f);
    unsigned s = (u >> 31) << 7;
    unsigned mag = u & 0x7fffffffu;
    unsigned q = (mag + 0x7FFFFu + ((mag >> 20) & 1u)) >> 20;
    int e8 = (int)(q >> 3) - 120;
    if (e8 >= 1) return s | ((unsigned)e8 << 3) | (q & 7u);   // normal
    float t = __uint_as_float(mag) * 512.0f;                  // subnormal
    return s | (unsigned)rintf(t);
}

__device__ __forceinline__ void gload16(const unsigned char* g, unsigned char* l) {
    __builtin_amdgcn_global_load_lds(
        (const __attribute__((address_space(1))) void*)g,
        (__attribute__((address_space(3))) void*)l, 16, 0, 0);
}

// ---------------- Kernel 1: normalize rows + positives -> fp8 reps ----------
// K-permuted fp8 layout per 64-col block: byte p = q*16 + h*8 + b holds
// k = b + h*32 + q*8, so one b128 read = {L half, H half} for that k-slot.
__global__ __launch_bounds__(256) void normalize_pos_kernel(
    const float* __restrict__ ei, const float* __restrict__ ej,
    unsigned char* __restrict__ reps, float* __restrict__ pos) {
    const int t = threadIdx.x & 63;
    const int i = blockIdx.x * 4 + (threadIdx.x >> 6);

    const float4* ri = (const float4*)(ei + (size_t)i * DIM);
    const float4* rj = (const float4*)(ej + (size_t)i * DIM);
    float4 a0 = ri[t], a1 = ri[t + 64];
    float4 b0 = rj[t], b1 = rj[t + 64];

    float si  = a0.x*a0.x + a0.y*a0.y + a0.z*a0.z + a0.w*a0.w
              + a1.x*a1.x + a1.y*a1.y + a1.z*a1.z + a1.w*a1.w;
    float sj  = b0.x*b0.x + b0.y*b0.y + b0.z*b0.z + b0.w*b0.w
              + b1.x*b1.x + b1.y*b1.y + b1.z*b1.z + b1.w*b1.w;
    float dij = a0.x*b0.x + a0.y*b0.y + a0.z*b0.z + a0.w*b0.w
              + a1.x*b1.x + a1.y*b1.y + a1.z*b1.z + a1.w*b1.w;

    #pragma unroll
    for (int m = 1; m < 64; m <<= 1) {
        si  += __shfl_xor(si,  m);
        sj  += __shfl_xor(sj,  m);
        dij += __shfl_xor(dij, m);
    }
    float invi = 1.0f / fmaxf(sqrtf(si), 1e-12f);
    float invj = 1.0f / fmaxf(sqrtf(sj), 1e-12f);

    const int off0 = (t >> 4) * 64 + ((t >> 1) & 3) * 16 + ((t >> 3) & 1) * 8 + 4 * (t & 1);

    unsigned wa0 = f2fp8(a0.x*invi) | (f2fp8(a0.y*invi) << 8)
                 | (f2fp8(a0.z*invi) << 16) | (f2fp8(a0.w*invi) << 24);
    unsigned wa1 = f2fp8(a1.x*invi) | (f2fp8(a1.y*invi) << 8)
                 | (f2fp8(a1.z*invi) << 16) | (f2fp8(a1.w*invi) << 24);
    unsigned wb0 = f2fp8(b0.x*invj) | (f2fp8(b0.y*invj) << 8)
                 | (f2fp8(b0.z*invj) << 16) | (f2fp8(b0.w*invj) << 24);
    unsigned wb1 = f2fp8(b1.x*invj) | (f2fp8(b1.y*invj) << 8)
                 | (f2fp8(b1.z*invj) << 16) | (f2fp8(b1.w*invj) << 24);

    unsigned char* wi = reps + (size_t)i * DIM;
    unsigned char* wj = reps + (size_t)(BATCH + i) * DIM;
    *(unsigned*)(wi + off0)       = wa0;
    *(unsigned*)(wi + off0 + 256) = wa1;
    *(unsigned*)(wj + off0)       = wb0;
    *(unsigned*)(wj + off0 + 256) = wb1;
    if (t == 0) pos[i] = dij * invi * invj;
}

// ---------------- Kernel 2: triangle 256x256 cells, fp8 MFMA ----------------
// r6's proven schedule (ring-4 slots, depth-3 prefetch, counted vmcnt(8),
// 1 barrier/K-step, 12 ds_read_b128 -> lgkm(0)). MFMA cluster reordered:
// L-pass over all 32 (m,n), then H-pass -> no back-to-back acc dependencies.
__global__ __launch_bounds__(512, 2) void simsum_kernel(
    const unsigned char* __restrict__ reps, float* __restrict__ partials) {
    __shared__ unsigned char lds[4][32768];   // slot: A [256][64B] | B [256][64B]

    int bid = (blockIdx.x & 7) * (NBLK / 8) + (blockIdx.x >> 3);  // 528 = 8*66
    int rc = 0, b = bid;
    while (b >= NCH - rc) { b -= NCH - rc; ++rc; }
    const int cc = rc + b;                    // rc <= cc
    const bool isDiag = (rc == cc);

    const int tid  = threadIdx.x;
    const int lane = tid & 63;
    const int wave = tid >> 6;
    const int wr = wave >> 2, wc = wave & 3;
    const int s = lane & 15, q = lane >> 4;
    const int rowBase = rc * TILE, colBase = cc * TILE;

    // staging: wave owns rows [32w,32w+32); pre-swizzled 16B-slot source
    const int lr = lane >> 2;
    const int gb = (((lane & 3) ^ ((lane >> 2) & 3) ^ (lane >> 4)) & 3) * 16;
    const unsigned char* gAw = reps + (size_t)(rowBase + wave * 32 + lr) * DIM + gb;
    const unsigned char* gBw = reps + (size_t)(colBase + wave * 32 + lr) * DIM + gb;

    // ds_read swizzled byte offsets (r6-verified conflict-free; 64B rows)
    const int sig  = ((s & 3) ^ (s >> 2)) & 3;
    const int koS  = ((q ^ sig) & 3) << 4;
    const int aoff = (wr * 128 + s) * 64 + koS;                // + m*1024
    const int boff = 16384 + (wc * 64 + s) * 64 + koS;         // + n*1024

    f32x4 acc[8][4];
    #pragma unroll
    for (int m = 0; m < 8; ++m)
        #pragma unroll
        for (int n = 0; n < 4; ++n) acc[m][n] = (f32x4){0.f,0.f,0.f,0.f};

#define STAGE(t) do { \
        const int _kb = (t) * 64; \
        unsigned char* _sb = &lds[(t) & 3][0]; \
        gload16(gAw + _kb,             _sb + wave * 2048); \
        gload16(gAw + 16 * DIM + _kb,  _sb + wave * 2048 + 1024); \
        gload16(gBw + _kb,             _sb + 16384 + wave * 2048); \
        gload16(gBw + 16 * DIM + _kb,  _sb + 16384 + wave * 2048 + 1024); \
    } while (0)

    // prologue: stage K-steps 0,1,2 (12 gloads/wave)
    STAGE(0); STAGE(1); STAGE(2);

    #pragma unroll
    for (int t = 0; t < NT8; ++t) {
        if (t <= 5)       { asm volatile("s_waitcnt vmcnt(8)" ::: "memory"); }
        else if (t == 6)  { asm volatile("s_waitcnt vmcnt(4)" ::: "memory"); }
        else              { asm volatile("s_waitcnt vmcnt(0)" ::: "memory"); }
        __builtin_amdgcn_s_barrier();
        __builtin_amdgcn_sched_barrier(0);

        if (t + 3 < NT8) STAGE(t + 3);

        const char* base = (const char*)&lds[t & 3][0];
        long2v af[8], bf[4];
        #pragma unroll
        for (int m = 0; m < 8; ++m) af[m] = *(const long2v*)(base + aoff + m * 1024);
        #pragma unroll
        for (int n = 0; n < 4; ++n) bf[n] = *(const long2v*)(base + boff + n * 1024);

        asm volatile("s_waitcnt lgkmcnt(0)" ::: "memory");
        __builtin_amdgcn_sched_barrier(0);
        __builtin_amdgcn_s_setprio(1);
        // L-pass: k 0..31 for all 32 accs (no acc dependency chains)
        #pragma unroll
        for (int m = 0; m < 8; ++m)
            #pragma unroll
            for (int n = 0; n < 4; ++n)
                acc[m][n] = __builtin_amdgcn_mfma_f32_16x16x32_fp8_fp8(
                    af[m][0], bf[n][0], acc[m][n], 0, 0, 0);
        // H-pass: k 32..63 (each acc's L-update is 31 instructions upstream)
        #pragma unroll
        for (int m = 0; m < 8; ++m)
            #pragma unroll
            for (int n = 0; n < 4; ++n)
                acc[m][n] = __builtin_amdgcn_mfma_f32_16x16x32_fp8_fp8(
                    af[m][1], bf[n][1], acc[m][n], 0, 0, 0);
        __builtin_amdgcn_s_setprio(0);
    }
#undef STAGE

    // ---- epilogue: exp(sim/T); diag masked; row + col sums ----
    const float SCALE = 2.8853900817779268f;   // 2/ln2
    float* red = (float*)lds;
    __syncthreads();
    float colacc[4] = {0.f,0.f,0.f,0.f};
    #pragma unroll
    for (int m = 0; m < 8; ++m) {
        const int lrow0 = wr * 128 + m * 16 + (q << 2);
        const int grow0 = rowBase + lrow0;
        float rs[4] = {0.f,0.f,0.f,0.f};
        #pragma unroll
        for (int n = 0; n < 4; ++n) {
            const int gcol = colBase + wc * 64 + n * 16 + s;
            #pragma unroll
            for (int j = 0; j < 4; ++j) {
                float e = exp2f(acc[m][n][j] * SCALE);
                if (isDiag && (grow0 + j == gcol)) e = 0.f;
                rs[j] += e;
                colacc[n] += e;
            }
        }
        #pragma unroll
        for (int j = 0; j < 4; ++j) {
            float v = rs[j];
            v += __shfl_xor(v, 1); v += __shfl_xor(v, 2);
            v += __shfl_xor(v, 4); v += __shfl_xor(v, 8);
            if (s == 0) red[wc * 256 + lrow0 + j] = v;
        }
    }
    #pragma unroll
    for (int n = 0; n < 4; ++n) {
        float v = colacc[n];
        v += __shfl_xor(v, 16); v += __shfl_xor(v, 32);
        if (q == 0) red[1024 + wr * 256 + wc * 64 + n * 16 + s] = v;
    }
    __syncthreads();
    if (tid < 256) {
        partials[(size_t)cc * NROW + rowBase + tid] =
            red[tid] + red[256 + tid] + red[512 + tid] + red[768 + tid];
        if (!isDiag)
            partials[(size_t)rc * NROW + colBase + tid] =
                red[1024 + tid] + red[1280 + tid];
    }
}

// ---------------- Kernel 3a: per-row loss partial sums ----------------
__global__ __launch_bounds__(256) void rowloss_kernel(
    const float* __restrict__ partials, const float* __restrict__ pos,
    double* __restrict__ blocksum) {
    const int t = threadIdx.x;
    const int r = blockIdx.x * 256 + t;
    float denom = 0.f;
    #pragma unroll 8
    for (int c = 0; c < NSLOT; ++c)
        denom += partials[(size_t)c * NROW + r];
    double v = (double)(logf(denom) - 2.0f * pos[r & (BATCH - 1)]);
    __shared__ double redl[256];
    redl[t] = v;
    __syncthreads();
    for (int off = 128; off > 0; off >>= 1) {
        if (t < off) redl[t] += redl[t + off];
        __syncthreads();
    }
    if (t == 0) blocksum[blockIdx.x] = redl[0];
}

__global__ void final2_kernel(const double* __restrict__ blocksum,
                              float* __restrict__ out) {
    if (threadIdx.x == 0) {
        double ssum = 0.0;
        #pragma unroll
        for (int i = 0; i < NROW / 256; ++i) ssum += blocksum[i];
        out[0] = (float)(ssum / (double)NROW);
    }
}

extern "C" void kernel_launch(void* const* d_in, const int* in_sizes, int n_in,
                              void* d_out, int out_size, void* d_ws, size_t ws_size,
                              hipStream_t stream) {
    const float* ei = (const float*)d_in[0];
    const float* ej = (const float*)d_in[1];
    float* out = (float*)d_out;

    unsigned char* reps = (unsigned char*)d_ws;                         // 4 MB fp8
    float* pos      = (float*)((char*)d_ws + (size_t)NROW * DIM);       // 16 KB
    float* partials = pos + BATCH;                                      // 32*8192*4
    double* blocksum = (double*)(partials + (size_t)NSLOT * NROW);

    normalize_pos_kernel<<<BATCH / 4, 256, 0, stream>>>(ei, ej, reps, pos);
    simsum_kernel<<<NBLK, 512, 0, stream>>>(reps, partials);
    rowloss_kernel<<<NROW / 256, 256, 0, stream>>>(partials, pos, blocksum);
    final2_kernel<<<1, 64, 0, stream>>>(blocksum, out);
}